// Round 3
// baseline (1133.881 us; speedup 1.0000x reference)
//
#include <hip/hip_runtime.h>
#include <hip/hip_fp16.h>
#include <cstdint>
#include <cstddef>

#define N_NODES 100000
#define N_FEAT  512
#define HIDDEN  16
#define N_LABELS 64
#define N_EDGES 3200000

#define NB    782            // destination buckets of 128 nodes (100096 >= 100000)
#define NPAD  (NB * 128)     // 100096
#define CAP   4608           // per-bucket capacity; mean 4092, sigma~64 -> +8 sigma
#define EPB   4096           // edges per bin block
#define BIN_BLOCKS 782
#define SPLITK 4             // K-splits in gemm role (each does 128 of 512 cols)
#define GBLK  196            // gemm node-blocks: 196 * 512 = 100352 >= N_NODES

// ---------------- workspace layout (bytes), peak ~33.8 MB ----------------
// gcur  : NB ints             @ 0       (zeroed each iter)
// deg   : NPAD i32            @ 16K     non-self in-degree (zeroed each iter)
// xws   : NPAD*16 half        @ 420K    dis*(x@W1); reused as z
// hs    : NPAD*16 half        @ 3560K   dis*relu(h)
// tmp   : NB*CAP u32          @ 6700K   packed edges (src<<7 | dst&127), 14.4 MB
// part  : SPLITK*NPAD*16 half @ 20800K  gemm1 K-split partials (12.8 MB)
static const size_t O_GCUR = 0;
static const size_t O_DEG  = (size_t)16 << 10;
static const size_t O_XWS  = (size_t)420 << 10;
static const size_t O_HS   = (size_t)3560 << 10;
static const size_t O_TMP  = (size_t)6700 << 10;
static const size_t O_PART = (size_t)20800 << 10;
#define PART_STRIDE_H ((size_t)NPAD * 16)      // halves per split

// ---------------- k_bg: grid-fused {edge binning + degree count} || {split-K x@W1} ----------------
// blocks [0, 782): bin role (scatter/atomic-latency-bound). Bucketed writes:
// within a block, edges to one bucket get consecutive slots -> L2 write-combining
// (round-2 lesson: globally-random 4B scatter = 16x write amplification, 309 us).
// Degree counting is fire-and-forget L2 atomics on a 400 KB array (cheap).
// blocks [782, 1566): gemm role (HBM-read-bound on x, 204.8 MB).
struct BinSh {
    unsigned short barr[EPB];   // bucket id per edge (NB sentinel = drop)
    unsigned       pk[EPB];     // packed (src<<7 | dst&127), stashed pass 1
    int hist[NB + 1];
    int gbase[NB];
    int lcur[NB];
};
union SMemBG {
    BinSh bin;
    float xs[512 * 17];
};

__global__ __launch_bounds__(512) void k_bg(const int* __restrict__ frm,
                                            const int* __restrict__ to,
                                            int* __restrict__ gcur,
                                            int* __restrict__ deg,
                                            unsigned* __restrict__ tmp,
                                            const float* __restrict__ x,
                                            const float* __restrict__ W1,
                                            __half* __restrict__ part) {
    __shared__ SMemBG sm;
    const int t = threadIdx.x;
    const int bid = blockIdx.x;

    if (bid < BIN_BLOCKS) {
        // ---------------- bin role ----------------
        BinSh& B = sm.bin;
        const size_t e0 = (size_t)bid * EPB;

        for (int i = t; i < NB + 1; i += 512) B.hist[i] = 0;
        __syncthreads();

        #pragma unroll
        for (int i = t; i < EPB; i += 512) {
            size_t e = e0 + i;
            int b = NB;                       // sentinel: invalid / self-loop
            unsigned pk = 0;
            if (e < N_EDGES) {
                int f = frm[e], tt = to[e];
                if (f != tt) {
                    b = tt >> 7;
                    pk = ((unsigned)f << 7) | (unsigned)(tt & 127);
                    atomicAdd(&deg[tt], 1);   // fire-and-forget, L2-resident
                }
            }
            B.barr[i] = (unsigned short)b;
            B.pk[i] = pk;
            atomicAdd(&B.hist[b], 1);
        }
        __syncthreads();

        for (int b = t; b < NB; b += 512) {
            B.gbase[b] = atomicAdd(&gcur[b], B.hist[b]);
            B.lcur[b] = 0;
        }
        __syncthreads();

        #pragma unroll
        for (int i = t; i < EPB; i += 512) {
            int b = B.barr[i];
            if (b < NB) {
                int r = atomicAdd(&B.lcur[b], 1);
                int p = B.gbase[b] + r;
                if (p < CAP)
                    tmp[(size_t)b * CAP + p] = B.pk[i];
            }
        }
    } else {
        // ---------------- gemm role: part[s] = x[:, 128s:128s+128] @ W1[128s:...] ----------------
        const int g = bid - BIN_BLOCKS;       // 0..783
        const int split = g / GBLK;           // 0..3
        const int bx = g - split * GBLK;      // 0..195
        const int base = bx * 512;
        const int kb = split * 128;

        float acc[HIDDEN];
        #pragma unroll
        for (int j = 0; j < HIDDEN; ++j) acc[j] = 0.f;

        const int pr = t >> 2;                // 0..127
        const int pc = (t & 3) << 2;          // 0,4,8,12

        for (int kt = 0; kt < 8; ++kt) {      // 8 x KT=16 cols = 128
            __syncthreads();
            #pragma unroll
            for (int p = 0; p < 4; ++p) {
                int r = p * 128 + pr;
                int n = base + r;
                float4 v = make_float4(0.f, 0.f, 0.f, 0.f);
                if (n < N_NODES)
                    v = *(const float4*)(x + (size_t)n * N_FEAT + kb + kt * 16 + pc);
                sm.xs[r * 17 + pc + 0] = v.x;
                sm.xs[r * 17 + pc + 1] = v.y;
                sm.xs[r * 17 + pc + 2] = v.z;
                sm.xs[r * 17 + pc + 3] = v.w;
            }
            __syncthreads();
            #pragma unroll
            for (int kk = 0; kk < 16; ++kk) {
                float xv = sm.xs[t * 17 + kk];
                const float4* wr = (const float4*)(W1 + ((size_t)(kb + kt * 16 + kk) << 4));
                float4 wa = wr[0], wb = wr[1], wc = wr[2], wd = wr[3];
                acc[ 0] = fmaf(xv, wa.x, acc[ 0]);
                acc[ 1] = fmaf(xv, wa.y, acc[ 1]);
                acc[ 2] = fmaf(xv, wa.z, acc[ 2]);
                acc[ 3] = fmaf(xv, wa.w, acc[ 3]);
                acc[ 4] = fmaf(xv, wb.x, acc[ 4]);
                acc[ 5] = fmaf(xv, wb.y, acc[ 5]);
                acc[ 6] = fmaf(xv, wb.z, acc[ 6]);
                acc[ 7] = fmaf(xv, wb.w, acc[ 7]);
                acc[ 8] = fmaf(xv, wc.x, acc[ 8]);
                acc[ 9] = fmaf(xv, wc.y, acc[ 9]);
                acc[10] = fmaf(xv, wc.z, acc[10]);
                acc[11] = fmaf(xv, wc.w, acc[11]);
                acc[12] = fmaf(xv, wd.x, acc[12]);
                acc[13] = fmaf(xv, wd.y, acc[13]);
                acc[14] = fmaf(xv, wd.z, acc[14]);
                acc[15] = fmaf(xv, wd.w, acc[15]);
            }
        }
        int n = base + t;
        if (n < N_NODES) {
            __half2 h2[8];
            #pragma unroll
            for (int j = 0; j < 8; ++j)
                h2[j] = __float22half2_rn(make_float2(acc[2 * j], acc[2 * j + 1]));
            float4* o = (float4*)(part + (size_t)split * PART_STRIDE_H + (size_t)n * HIDDEN);
            o[0] = *(float4*)&h2[0];
            o[1] = *(float4*)&h2[4];
        }
    }
}

// ---------------- k_comb: xws = rsqrt(deg+1) * sum_s part[s]  (half2-vectorized) ----------------
__global__ __launch_bounds__(256) void k_comb(const __half2* __restrict__ part2,
                                              const int* __restrict__ deg,
                                              __half2* __restrict__ xws2) {
    int i = blockIdx.x * 256 + threadIdx.x;       // over N_NODES*8 half2
    if (i >= N_NODES * 8) return;
    const size_t st = (size_t)NPAD * 8;
    float2 a = __half22float2(part2[i]);
    float2 b = __half22float2(part2[st + i]);
    float2 c = __half22float2(part2[2 * st + i]);
    float2 d = __half22float2(part2[3 * st + i]);
    float dn = rsqrtf((float)deg[i >> 3] + 1.0f);
    xws2[i] = __float22half2_rn(make_float2(dn * (a.x + b.x + c.x + d.x),
                                            dn * (a.y + b.y + c.y + d.y)));
}

// ---------------- k_agg: bucket-LDS aggregation over UNSORTED packed edges ----------------
// One block per 128-node bucket. acc[128][16] fp32 in LDS (stride 17 vs bank
// conflicts). Per edge: 16-lane group gathers rows[src][:] (32 B, L2-resident
// 3.2 MB table) and ds_add_f32 fire-and-forget into acc[dst_local][:].
// Replaces the entire counting sort + per-node segment machinery.
__global__ __launch_bounds__(512) void k_agg(const __half* __restrict__ rows,
                                             const unsigned* __restrict__ tmp,
                                             const int* __restrict__ gcur,
                                             const int* __restrict__ deg,
                                             const float* __restrict__ bias,
                                             __half* __restrict__ outp,
                                             int mode) {
    __shared__ float acc[128 * 17];
    const int t = threadIdx.x;
    const int b = blockIdx.x;
    const int n_e = min(gcur[b], CAP);
    const unsigned* seg = tmp + (size_t)b * CAP;

    #pragma unroll
    for (int i = t; i < 128 * 17; i += 512) acc[i] = 0.f;
    __syncthreads();

    const int lane = t & 15, g = t >> 4;          // 32 groups of 16 lanes
    for (int i = g; i < n_e; i += 32) {
        unsigned w = seg[i];
        float v = __half2float(rows[(size_t)(w >> 7) * HIDDEN + lane]);
        atomicAdd(&acc[(w & 127u) * 17 + lane], v);
    }
    __syncthreads();

    #pragma unroll
    for (int i = t; i < 2048; i += 512) {
        int nl = i >> 4, ln = i & 15;
        int n = b * 128 + nl;
        if (n < N_NODES) {
            float dn = rsqrtf((float)deg[n] + 1.0f);
            float sum = acc[nl * 17 + ln] + __half2float(rows[(size_t)n * HIDDEN + ln]);
            float v;
            if (mode) v = fmaxf(fmaf(dn, sum, bias[ln]), 0.f) * dn;
            else      v = dn * sum;
            outp[(size_t)n * HIDDEN + ln] = __float2half(v);
        }
    }
}

// ---------------- logits = z @ W2 + b2, fused log_softmax ----------------
__global__ __launch_bounds__(256) void k_out(const __half* __restrict__ z,
                                             const float* __restrict__ W2,
                                             const float* __restrict__ b2,
                                             float* __restrict__ out) {
    int gt = blockIdx.x * 256 + threadIdx.x;
    int n = gt >> 6;
    int j = gt & 63;
    float acc = b2[j];
    const __half* zr = z + (size_t)n * HIDDEN;
    #pragma unroll
    for (int k = 0; k < HIDDEN; ++k)
        acc = fmaf(__half2float(zr[k]), W2[k * N_LABELS + j], acc);
    float m = acc;
    #pragma unroll
    for (int off = 32; off > 0; off >>= 1)
        m = fmaxf(m, __shfl_xor(m, off, 64));
    float ex = __expf(acc - m);
    float sum = ex;
    #pragma unroll
    for (int off = 32; off > 0; off >>= 1)
        sum += __shfl_xor(sum, off, 64);
    out[(size_t)n * N_LABELS + j] = acc - m - __logf(sum);
}

// ---------------- launch ----------------
extern "C" void kernel_launch(void* const* d_in, const int* in_sizes, int n_in,
                              void* d_out, int out_size, void* d_ws, size_t ws_size,
                              hipStream_t stream) {
    const float* x  = (const float*)d_in[0];
    const int*   ei = (const int*)d_in[1];
    const float* W1 = (const float*)d_in[2];
    const float* b1 = (const float*)d_in[3];
    const float* W2 = (const float*)d_in[4];
    const float* b2 = (const float*)d_in[5];
    float* out = (float*)d_out;
    char*  ws  = (char*)d_ws;

    int*      gcur = (int*)(ws + O_GCUR);
    int*      deg  = (int*)(ws + O_DEG);
    __half*   xws  = (__half*)(ws + O_XWS);   // xws; reused as z after 2nd k_agg
    __half*   hs   = (__half*)(ws + O_HS);
    unsigned* tmp  = (unsigned*)(ws + O_TMP);
    __half*   part = (__half*)(ws + O_PART);

    const int* frm = ei;
    const int* to  = ei + N_EDGES;

    // zero gcur + deg in one call
    hipMemsetAsync(ws, 0, O_DEG + (size_t)NPAD * sizeof(int), stream);

    k_bg   <<<BIN_BLOCKS + SPLITK * GBLK, 512, 0, stream>>>(frm, to, gcur, deg, tmp, x, W1, part);
    k_comb <<<3125, 256, 0, stream>>>((const __half2*)part, deg, (__half2*)xws);
    k_agg  <<<NB, 512, 0, stream>>>(xws, tmp, gcur, deg, b1, hs, 1);
    k_agg  <<<NB, 512, 0, stream>>>(hs, tmp, gcur, deg, b1, xws, 0);
    k_out  <<<N_NODES / 4, 256, 0, stream>>>(xws, W2, b2, out);
}

// Round 5
// 445.587 us; speedup vs baseline: 2.5447x; 2.5447x over previous
//
#include <hip/hip_runtime.h>
#include <hip/hip_fp16.h>
#include <cstdint>
#include <cstddef>

#define N_NODES 100000
#define N_FEAT  512
#define HIDDEN  16
#define N_LABELS 64
#define N_EDGES 3200000

#define NB    782            // destination buckets of 128 nodes (100096 >= 100000)
#define NPAD  (NB * 128)     // 100096
#define CAP   4608           // per-bucket capacity; mean 4092, sigma~64 -> +8 sigma
#define EPB   4096           // edges per bin block
#define BIN_BLOCKS 782
#define SPLITK 4             // K-splits in gemm role (each does 128 of 512 cols)
#define GBLK  196            // gemm node-blocks: 196 * 512 = 100352 >= N_NODES

// ---------------- workspace layout (bytes), total ~34.1 MB ----------------
static const size_t O_GCUR = 0;                  // NB ints (zeroed each iter)
static const size_t O_DIS  = (size_t)16 << 10;   // NPAD f32
static const size_t O_STA  = (size_t)420 << 10;  // NPAD int
static const size_t O_END  = (size_t)824 << 10;  // NPAD int
static const size_t O_XWS  = (size_t)1228 << 10; // NPAD*16 half  dis*(x@W1)
static const size_t O_HS   = (size_t)4360 << 10; // NPAD*16 half  dis*relu(h)
static const size_t O_TMP  = (size_t)7492 << 10; // NB*CAP u32    packed/sorted edges
static const size_t O_PART = (size_t)21572 << 10;// SPLITK*NPAD*16 half gemm1 partials
#define PART_STRIDE_H ((size_t)NPAD * 16)        // halves per split

// ---------------- k_bg: grid-fused {edge binning} || {split-K x@W1} ----------------
// blocks [0, 782): bin role. Pass 1's hist atomic RETURN is the edge's
// within-block rank -> stash it; pass 3 (replay) is pure load+store,
// no lcur atomic chain (was a return-dependent LDS atomic per edge).
// blocks [782, 1566): gemm role (HBM-read-bound on x, 204.8 MB).
// LDS union = max(39028 bin, 34816 gemm) -> 4 blocks/CU (156 KB of 160 KB).
struct BinSh {
    unsigned short barr[EPB];   // bucket id per edge (NB sentinel = drop)
    unsigned short rank[EPB];   // within-block rank in bucket (from hist atomic)
    unsigned       pk[EPB];     // packed (src<<7 | dst&127), stashed pass 1
    int hist[NB + 1];
    int gbase[NB];
};
union SMemBG {
    BinSh bin;
    float xs[512 * 17];
};

__global__ __launch_bounds__(512) void k_bg(const int* __restrict__ frm,
                                            const int* __restrict__ to,
                                            int* __restrict__ gcur,
                                            unsigned* __restrict__ tmp,
                                            const float* __restrict__ x,
                                            const float* __restrict__ W1,
                                            __half* __restrict__ part) {
    __shared__ SMemBG sm;
    const int t = threadIdx.x;
    const int bid = blockIdx.x;

    if (bid < BIN_BLOCKS) {
        // ---------------- bin role ----------------
        BinSh& B = sm.bin;
        const size_t e0 = (size_t)bid * EPB;

        for (int i = t; i < NB + 1; i += 512) B.hist[i] = 0;
        __syncthreads();

        #pragma unroll
        for (int i = t; i < EPB; i += 512) {
            size_t e = e0 + i;
            int b = NB;                       // sentinel: invalid / self-loop
            unsigned pk = 0;
            if (e < N_EDGES) {
                int f = frm[e], tt = to[e];
                if (f != tt) {
                    b = tt >> 7;
                    pk = ((unsigned)f << 7) | (unsigned)(tt & 127);
                }
            }
            int r = atomicAdd(&B.hist[b], 1); // rank within block's bucket
            B.barr[i] = (unsigned short)b;
            B.rank[i] = (unsigned short)r;
            B.pk[i]   = pk;
        }
        __syncthreads();

        for (int b = t; b < NB; b += 512)
            B.gbase[b] = atomicAdd(&gcur[b], B.hist[b]);
        __syncthreads();

        #pragma unroll
        for (int i = t; i < EPB; i += 512) {
            int b = B.barr[i];
            if (b < NB) {
                int p = B.gbase[b] + (int)B.rank[i];
                if (p < CAP)
                    tmp[(size_t)b * CAP + p] = B.pk[i];   // no atomics here
            }
        }
    } else {
        // ---------------- gemm role: part[s] = x[:, 128s:128s+128] @ W1[128s:...] ----------------
        const int g = bid - BIN_BLOCKS;       // 0..783
        const int split = g / GBLK;           // 0..3
        const int bx = g - split * GBLK;      // 0..195
        const int base = bx * 512;
        const int kb = split * 128;

        float acc[HIDDEN];
        #pragma unroll
        for (int j = 0; j < HIDDEN; ++j) acc[j] = 0.f;

        const int pr = t >> 2;                // 0..127
        const int pc = (t & 3) << 2;          // 0,4,8,12

        for (int kt = 0; kt < 8; ++kt) {      // 8 x KT=16 cols = 128
            __syncthreads();
            #pragma unroll
            for (int p = 0; p < 4; ++p) {
                int r = p * 128 + pr;
                int n = base + r;
                float4 v = make_float4(0.f, 0.f, 0.f, 0.f);
                if (n < N_NODES)
                    v = *(const float4*)(x + (size_t)n * N_FEAT + kb + kt * 16 + pc);
                sm.xs[r * 17 + pc + 0] = v.x;
                sm.xs[r * 17 + pc + 1] = v.y;
                sm.xs[r * 17 + pc + 2] = v.z;
                sm.xs[r * 17 + pc + 3] = v.w;
            }
            __syncthreads();
            #pragma unroll
            for (int kk = 0; kk < 16; ++kk) {
                float xv = sm.xs[t * 17 + kk];
                const float4* wr = (const float4*)(W1 + ((size_t)(kb + kt * 16 + kk) << 4));
                float4 wa = wr[0], wb = wr[1], wc = wr[2], wd = wr[3];
                acc[ 0] = fmaf(xv, wa.x, acc[ 0]);
                acc[ 1] = fmaf(xv, wa.y, acc[ 1]);
                acc[ 2] = fmaf(xv, wa.z, acc[ 2]);
                acc[ 3] = fmaf(xv, wa.w, acc[ 3]);
                acc[ 4] = fmaf(xv, wb.x, acc[ 4]);
                acc[ 5] = fmaf(xv, wb.y, acc[ 5]);
                acc[ 6] = fmaf(xv, wb.z, acc[ 6]);
                acc[ 7] = fmaf(xv, wb.w, acc[ 7]);
                acc[ 8] = fmaf(xv, wc.x, acc[ 8]);
                acc[ 9] = fmaf(xv, wc.y, acc[ 9]);
                acc[10] = fmaf(xv, wc.z, acc[10]);
                acc[11] = fmaf(xv, wc.w, acc[11]);
                acc[12] = fmaf(xv, wd.x, acc[12]);
                acc[13] = fmaf(xv, wd.y, acc[13]);
                acc[14] = fmaf(xv, wd.z, acc[14]);
                acc[15] = fmaf(xv, wd.w, acc[15]);
            }
        }
        int n = base + t;
        if (n < N_NODES) {
            __half2 h2[8];
            #pragma unroll
            for (int j = 0; j < 8; ++j)
                h2[j] = __float22half2_rn(make_float2(acc[2 * j], acc[2 * j + 1]));
            float4* o = (float4*)(part + (size_t)split * PART_STRIDE_H + (size_t)n * HIDDEN);
            o[0] = *(float4*)&h2[0];
            o[1] = *(float4*)&h2[4];
        }
    }
}

// ---------------- k_sort: in-place counting sort of each bucket by dest ----------------
__global__ __launch_bounds__(512) void k_sort(unsigned* __restrict__ tmp,
                                              const int* __restrict__ gcur,
                                              int* __restrict__ starts,
                                              int* __restrict__ ends,
                                              float* __restrict__ dis) {
    __shared__ unsigned stage[CAP];
    __shared__ int cnt[128];
    __shared__ int sc[128];
    __shared__ int lcur[128];
    const int t = threadIdx.x, b = blockIdx.x;
    const int n_e = min(gcur[b], CAP);
    unsigned* seg = tmp + (size_t)b * CAP;

    if (t < 128) { cnt[t] = 0; lcur[t] = 0; }
    __syncthreads();

    for (int i = t; i < n_e; i += 512) {
        unsigned w = seg[i];
        stage[i] = w;
        atomicAdd(&cnt[w & 127u], 1);
    }
    __syncthreads();

    if (t < 128) sc[t] = cnt[t];
    __syncthreads();
    #pragma unroll
    for (int off = 1; off < 128; off <<= 1) {
        int a = 0;
        if (t < 128 && t >= off) a = sc[t - off];
        __syncthreads();
        if (t < 128) sc[t] += a;
        __syncthreads();
    }

    if (t < 128) {
        int excl = sc[t] - cnt[t];
        int node = b * 128 + t;
        int s0 = b * CAP + excl;
        starts[node] = s0;
        ends[node]   = s0 + cnt[t];
        dis[node]    = rsqrtf((float)cnt[t] + 1.0f);
    }
    __syncthreads();

    for (int i = t; i < n_e; i += 512) {
        unsigned w = stage[i];
        int tl = (int)(w & 127u);
        int p = atomicAdd(&lcur[tl], 1);
        seg[(sc[tl] - cnt[tl]) + p] = w >> 7;   // plain source node id
    }
}

// ---------------- k_comb: xws = dis * sum_s part[s]  (half2-vectorized) ----------------
__global__ __launch_bounds__(256) void k_comb(const __half2* __restrict__ part2,
                                              const float* __restrict__ dis,
                                              __half2* __restrict__ xws2) {
    int i = blockIdx.x * 256 + threadIdx.x;       // over N_NODES*8 half2
    if (i >= N_NODES * 8) return;
    const size_t st = (size_t)NPAD * 8;
    float2 a = __half22float2(part2[i]);
    float2 b = __half22float2(part2[st + i]);
    float2 c = __half22float2(part2[2 * st + i]);
    float2 d = __half22float2(part2[3 * st + i]);
    float dn = dis[i >> 3];
    xws2[i] = __float22half2_rn(make_float2(dn * (a.x + b.x + c.x + d.x),
                                            dn * (a.y + b.y + c.y + d.y)));
}

// ---------------- k_agg1: layer-1 aggregation, relu epilogue -> hs ----------------
__global__ __launch_bounds__(512) void k_agg1(const __half* __restrict__ rows,
                                              const unsigned* __restrict__ sorted,
                                              const int* __restrict__ starts,
                                              const int* __restrict__ ends,
                                              const float* __restrict__ dis,
                                              const float* __restrict__ bias,
                                              __half* __restrict__ outp) {
    const int t = threadIdx.x;
    const int lane = t & 15, g = t >> 4;
    const int n = blockIdx.x * 32 + g;
    const int s0 = starts[n], e0 = ends[n];
    float acc = 0.f;
    for (int base = s0; base < e0; base += 16) {
        int idx = base + lane;
        unsigned f = (idx < e0) ? sorted[idx] : 0u;
        int cnt = min(16, e0 - base);
        #pragma unroll
        for (int q = 0; q < 16; ++q) {
            unsigned fq = __shfl(f, q, 16);
            float v = __half2float(rows[(size_t)fq * HIDDEN + lane]);
            if (q < cnt) acc += v;
        }
    }
    if (n < N_NODES) {
        float dn = dis[n];
        float sum = acc + __half2float(rows[(size_t)n * HIDDEN + lane]);
        float v = fmaxf(fmaf(dn, sum, bias[lane]), 0.f) * dn;   // *dn pre-applies src-scale for layer 2
        outp[(size_t)n * HIDDEN + lane] = __float2half(v);
    }
}

// ---------------- k_agg2o: layer-2 aggregation FUSED with z@W2+b2 and log_softmax ----------------
// After the gather, each 16-lane group holds z[n][lane] in fp32. The 16x64 W2
// matmul is done via width-16 shfl broadcast (64 FMA/lane); log-softmax reduces
// across the group with shfl_xor. Kills k_out + the z half round-trip.
__global__ __launch_bounds__(512) void k_agg2o(const __half* __restrict__ rows,
                                               const unsigned* __restrict__ sorted,
                                               const int* __restrict__ starts,
                                               const int* __restrict__ ends,
                                               const float* __restrict__ dis,
                                               const float* __restrict__ W2,
                                               const float* __restrict__ b2,
                                               float* __restrict__ out) {
    const int t = threadIdx.x;
    const int lane = t & 15, g = t >> 4;
    const int n = blockIdx.x * 32 + g;
    const int s0 = starts[n], e0 = ends[n];
    float acc = 0.f;
    for (int base = s0; base < e0; base += 16) {
        int idx = base + lane;
        unsigned f = (idx < e0) ? sorted[idx] : 0u;
        int cnt = min(16, e0 - base);
        #pragma unroll
        for (int q = 0; q < 16; ++q) {
            unsigned fq = __shfl(f, q, 16);
            float v = __half2float(rows[(size_t)fq * HIDDEN + lane]);
            if (q < cnt) acc += v;
        }
    }
    // z[n][lane] in fp32 (rows = hs already carries the src-side dis factor)
    float dn = (n < N_NODES) ? dis[n] : 1.f;
    float z = dn * (acc + __half2float(rows[(size_t)n * HIDDEN + lane]));

    // logits: o_r = b2[lane+16r] + sum_k z_k * W2[k][lane+16r]
    float o0 = b2[lane], o1 = b2[lane + 16], o2 = b2[lane + 32], o3 = b2[lane + 48];
    #pragma unroll
    for (int k = 0; k < HIDDEN; ++k) {
        float zk = __shfl(z, k, 16);
        const float* wr = W2 + k * N_LABELS;
        o0 = fmaf(zk, wr[lane],      o0);
        o1 = fmaf(zk, wr[lane + 16], o1);
        o2 = fmaf(zk, wr[lane + 32], o2);
        o3 = fmaf(zk, wr[lane + 48], o3);
    }
    // log_softmax over the 64 logits living as 4 regs x 16 lanes
    float m = fmaxf(fmaxf(o0, o1), fmaxf(o2, o3));
    #pragma unroll
    for (int off = 8; off > 0; off >>= 1)
        m = fmaxf(m, __shfl_xor(m, off, 16));
    float s = __expf(o0 - m) + __expf(o1 - m) + __expf(o2 - m) + __expf(o3 - m);
    #pragma unroll
    for (int off = 8; off > 0; off >>= 1)
        s += __shfl_xor(s, off, 16);
    float ls = m + __logf(s);

    if (n < N_NODES) {
        float* orow = out + (size_t)n * N_LABELS;
        orow[lane]      = o0 - ls;
        orow[lane + 16] = o1 - ls;
        orow[lane + 32] = o2 - ls;
        orow[lane + 48] = o3 - ls;
    }
}

// ---------------- launch ----------------
extern "C" void kernel_launch(void* const* d_in, const int* in_sizes, int n_in,
                              void* d_out, int out_size, void* d_ws, size_t ws_size,
                              hipStream_t stream) {
    const float* x  = (const float*)d_in[0];
    const int*   ei = (const int*)d_in[1];
    const float* W1 = (const float*)d_in[2];
    const float* b1 = (const float*)d_in[3];
    const float* W2 = (const float*)d_in[4];
    const float* b2 = (const float*)d_in[5];
    float* out = (float*)d_out;
    char*  ws  = (char*)d_ws;

    int*      gcur   = (int*)(ws + O_GCUR);
    float*    dis    = (float*)(ws + O_DIS);
    int*      starts = (int*)(ws + O_STA);
    int*      ends   = (int*)(ws + O_END);
    __half*   xws    = (__half*)(ws + O_XWS);
    __half*   hs     = (__half*)(ws + O_HS);
    unsigned* tmp    = (unsigned*)(ws + O_TMP);
    __half*   part   = (__half*)(ws + O_PART);

    const int* frm = ei;
    const int* to  = ei + N_EDGES;

    hipMemsetAsync(gcur, 0, NB * sizeof(int), stream);

    k_bg    <<<BIN_BLOCKS + SPLITK * GBLK, 512, 0, stream>>>(frm, to, gcur, tmp, x, W1, part);
    k_sort  <<<NB, 512, 0, stream>>>(tmp, gcur, starts, ends, dis);
    k_comb  <<<3125, 256, 0, stream>>>((const __half2*)part, dis, (__half2*)xws);
    k_agg1  <<<NPAD / 32, 512, 0, stream>>>(xws, tmp, starts, ends, dis, b1, hs);
    k_agg2o <<<NPAD / 32, 512, 0, stream>>>(hs, tmp, starts, ends, dis, W2, b2, out);
}